// Round 1
// baseline (838.574 us; speedup 1.0000x reference)
//
#include <hip/hip_runtime.h>

#define N 2048
#define D 64
#define BH 16
#define NWORDS 3126          // bitmap words over r in [0,100000]
#define ROWS 16              // score rows per block
#define SCP 2052             // score-row pitch in floats (+4 pad -> bank rotation)
#define AUXW (2 * NWORDS)    // 6252 words multi-purpose LDS (qstage/bitmaps/vstage/scratch)

typedef __bf16 bf16x8 __attribute__((ext_vector_type(8)));
typedef float f32x4 __attribute__((ext_vector_type(4)));

union Bf16x8U {
  bf16x8 v;
  __bf16 e[8];
  unsigned short us[8];
};

// Split 8 fp32 (two float4) into hi/lo bf16 fragments: f = hi + lo + O(2^-16 f)
static __device__ inline void split8(const float4& a, const float4& b,
                                     bf16x8& hi, bf16x8& lo) {
  float f[8] = {a.x, a.y, a.z, a.w, b.x, b.y, b.z, b.w};
  Bf16x8U h, l;
#pragma unroll
  for (int i = 0; i < 8; ++i) {
    __bf16 hb = (__bf16)f[i];
    h.e[i] = hb;
    l.e[i] = (__bf16)(f[i] - (float)hb);
  }
  hi = h.v;
  lo = l.v;
}

// ---------------------------------------------------------------------------
// Fully fused attention: one block owns 16 score rows; the 16x2048 fp32 score
// tile lives entirely in LDS. Raw scores never touch HBM; attn_p is written
// exactly once (mandatory output traffic).
// 512 threads = 8 waves. Grid (N/16, BH). ~153 KiB LDS -> 1 block/CU.
// ---------------------------------------------------------------------------
__global__ __launch_bounds__(512) void fused_attn(
    const float* __restrict__ q, const float* __restrict__ k,
    const float* __restrict__ v, float* __restrict__ outp,
    float* __restrict__ attnp) {
  __shared__ float sc[ROWS * SCP];   // 131,328 B score tile
  __shared__ unsigned aux[AUXW];     // 25,008 B: P1 q-stage / P3 2 bitmaps / P4 v-stage+scratch
  __shared__ float rowmax[ROWS];
  __shared__ float rowsum[ROWS];

  const int h = blockIdx.y;
  const int row0 = blockIdx.x * ROWS;
  const float* qh = q + (size_t)h * N * D;
  const float* kh = k + (size_t)h * N * D;
  const float* vh = v + (size_t)h * N * D;

  const int t = threadIdx.x;
  const int wave = t >> 6;
  const int lane = t & 63;
  const int m = lane & 15;
  const int quad = lane >> 4;

  // ================= Phase 1: sc = (q/8) @ k^T (split-bf16 MFMA) ===========
  {
    float* qlds = (float*)aux;  // [16][68] scaled q tile (pitch 68 breaks banks)
    if (t < 256) {
      const int qr = t >> 4;
      const int qc = (t & 15) * 4;
      float4 vv = *(const float4*)(qh + (size_t)(row0 + qr) * D + qc);
      vv.x *= 0.125f; vv.y *= 0.125f; vv.z *= 0.125f; vv.w *= 0.125f;
      *(float4*)&qlds[qr * 68 + qc] = vv;
    }
    __syncthreads();

    bf16x8 ahi0, alo0, ahi1, alo1;
    {
      const float* qp = &qlds[m * 68 + quad * 8];
      float4 a00 = *(const float4*)(qp);
      float4 a01 = *(const float4*)(qp + 4);
      float4 a10 = *(const float4*)(qp + 32);
      float4 a11 = *(const float4*)(qp + 36);
      split8(a00, a01, ahi0, alo0);
      split8(a10, a11, ahi1, alo1);
    }

    const int colbase = wave * 256;  // wave covers 16 col-tiles
    float4 c0, c1, c2, c3, p0, p1, p2, p3;
    {
      const float* kr = kh + (size_t)(colbase + m) * D + quad * 8;
      c0 = *(const float4*)(kr);
      c1 = *(const float4*)(kr + 4);
      c2 = *(const float4*)(kr + 32);
      c3 = *(const float4*)(kr + 36);
    }
#pragma unroll
    for (int ct = 0; ct < 16; ++ct) {
      if (ct < 15) {  // 1-deep prefetch of next k tile
        const float* kr = kh + (size_t)(colbase + (ct + 1) * 16 + m) * D + quad * 8;
        p0 = *(const float4*)(kr);
        p1 = *(const float4*)(kr + 4);
        p2 = *(const float4*)(kr + 32);
        p3 = *(const float4*)(kr + 36);
      }
      bf16x8 bhi0, blo0, bhi1, blo1;
      split8(c0, c1, bhi0, blo0);
      split8(c2, c3, bhi1, blo1);
      f32x4 acc = {0.f, 0.f, 0.f, 0.f};
      // same accumulation order as the verified qk_kernel
      acc = __builtin_amdgcn_mfma_f32_16x16x32_bf16(alo0, bhi0, acc, 0, 0, 0);
      acc = __builtin_amdgcn_mfma_f32_16x16x32_bf16(alo1, bhi1, acc, 0, 0, 0);
      acc = __builtin_amdgcn_mfma_f32_16x16x32_bf16(ahi0, blo0, acc, 0, 0, 0);
      acc = __builtin_amdgcn_mfma_f32_16x16x32_bf16(ahi1, blo1, acc, 0, 0, 0);
      acc = __builtin_amdgcn_mfma_f32_16x16x32_bf16(ahi0, bhi0, acc, 0, 0, 0);
      acc = __builtin_amdgcn_mfma_f32_16x16x32_bf16(ahi1, bhi1, acc, 0, 0, 0);
      const int cb = colbase + ct * 16 + m;
#pragma unroll
      for (int r = 0; r < 4; ++r) sc[(quad * 4 + r) * SCP + cb] = acc[r];
      c0 = p0; c1 = p1; c2 = p2; c3 = p3;
    }
  }
  __syncthreads();

  // ================= Phase 2: per-row max (wave w -> rows w, w+8) ==========
#pragma unroll
  for (int rr = 0; rr < 2; ++rr) {
    const int r = wave + rr * 8;
    const float* rowp = &sc[r * SCP];
    float mx = -3.4e38f;
#pragma unroll
    for (int i = 0; i < 8; ++i) {
      float4 vv = *(const float4*)&rowp[(lane + i * 64) * 4];
      mx = fmaxf(mx, fmaxf(fmaxf(vv.x, vv.y), fmaxf(vv.z, vv.w)));
    }
#pragma unroll
    for (int o = 32; o > 0; o >>= 1) mx = fmaxf(mx, __shfl_xor(mx, o, 64));
    if (lane == 0) rowmax[r] = mx;
  }
  __syncthreads();

  // ========== Phase 3: exp -> round -> bitmap dedup-sum (2 rows/round) =====
  {
    const int g = wave >> 2;   // bitmap group: waves 0-3 -> rows 0..7, 4-7 -> 8..15
    const int tt = t & 255;    // thread index within group (256 thr per row)
    unsigned* bm = aux + g * NWORDS;
#pragma unroll 1
    for (int it = 0; it < 8; ++it) {
      const int r = it + g * 8;
      for (int i = tt; i < NWORDS; i += 256) bm[i] = 0u;
      if (tt == 0) rowsum[r] = 0.0f;
      __syncthreads();
      const float mrow = rowmax[r];
      float* rowp = &sc[r * SCP];
      float4 x0 = *(const float4*)&rowp[tt * 4];
      float4 x1 = *(const float4*)&rowp[1024 + tt * 4];
      float xs[8] = {x0.x, x0.y, x0.z, x0.w, x1.x, x1.y, x1.z, x1.w};
      float xr[8];
      float lsum = 0.0f;
#pragma unroll
      for (int j = 0; j < 8; ++j) {
        float ex = expf(xs[j] - mrow);           // <= 1.0
        float rf = rintf(ex * 100000.0f);        // round-half-even, exact in fp32
        float xv = rf / 100000.0f;               // match reference fp32 divide
        xr[j] = xv;
        int ri = (int)rf;                        // 0..100000
        unsigned mask = 1u << (ri & 31);
        unsigned old = atomicOr(&bm[ri >> 5], mask);
        if (!(old & mask)) lsum += xv;           // each distinct value once
      }
      // write rounded values back (PV consumes unnormalized xv from LDS)
      *(float4*)&rowp[tt * 4] = make_float4(xr[0], xr[1], xr[2], xr[3]);
      *(float4*)&rowp[1024 + tt * 4] = make_float4(xr[4], xr[5], xr[6], xr[7]);
#pragma unroll
      for (int o = 32; o > 0; o >>= 1) lsum += __shfl_xor(lsum, o, 64);
      if (lane == 0) atomicAdd(&rowsum[r], lsum);
      __syncthreads();
    }
  }

  // ===== Phase 4a: attn_p = xv/total -> global (fire-and-forget stores) ====
#pragma unroll
  for (int rr = 0; rr < 2; ++rr) {
    const int r = wave + rr * 8;
    const float tot = rowsum[r];
    const float* rowp = &sc[r * SCP];
    float4* dst = (float4*)(attnp + ((size_t)h * N + row0 + r) * N);
#pragma unroll
    for (int i = 0; i < 8; ++i) {
      float4 vv = *(const float4*)&rowp[(lane + i * 64) * 4];
      dst[lane + i * 64] = make_float4(vv.x / tot, vv.y / tot, vv.z / tot, vv.w / tot);
    }
  }

  // ===== Phase 4b: PV on unnormalized xv; out = (sum xv*v)/total ===========
  {
    unsigned short* vH = (unsigned short*)aux;  // [64 n][72 k] hi-bf16 of v chunk
    unsigned short* vL = vH + 64 * 72;          // lo-bf16 (offset 9216 B, 16B aligned)
    const int skk = t >> 4;                     // staging k row 0..31 (+32)
    const int snn = (t & 15) * 4;               // staging col group
    const int ctn = wave & 3;                   // col-tile of this wave
    const int ksub = wave >> 2;                 // K-half within 64-chunk
    const int n0 = ctn * 16;
    f32x4 acc = {0.f, 0.f, 0.f, 0.f};

    float4 nva = *(const float4*)(vh + (size_t)skk * D + snn);
    float4 nvb = *(const float4*)(vh + (size_t)(skk + 32) * D + snn);

#pragma unroll 1
    for (int k0 = 0; k0 < N; k0 += 64) {
      {  // pack current chunk into split hi/lo LDS ([n][k] => B-frag = 1 b128 each)
        float fa[4] = {nva.x, nva.y, nva.z, nva.w};
        float fb[4] = {nvb.x, nvb.y, nvb.z, nvb.w};
#pragma unroll
        for (int j = 0; j < 4; ++j) {
          __bf16 ha = (__bf16)fa[j];
          __bf16 la = (__bf16)(fa[j] - (float)ha);
          vH[(snn + j) * 72 + skk] = __builtin_bit_cast(unsigned short, ha);
          vL[(snn + j) * 72 + skk] = __builtin_bit_cast(unsigned short, la);
          __bf16 hb2 = (__bf16)fb[j];
          __bf16 lb2 = (__bf16)(fb[j] - (float)hb2);
          vH[(snn + j) * 72 + skk + 32] = __builtin_bit_cast(unsigned short, hb2);
          vL[(snn + j) * 72 + skk + 32] = __builtin_bit_cast(unsigned short, lb2);
        }
      }
      if (k0 + 64 < N) {  // issue next chunk loads; latency hides under compute
        nva = *(const float4*)(vh + (size_t)(k0 + 64 + skk) * D + snn);
        nvb = *(const float4*)(vh + (size_t)(k0 + 64 + skk + 32) * D + snn);
      }
      __syncthreads();

      const float* ap = &sc[(size_t)m * SCP + k0 + ksub * 32 + quad * 8];
      float4 a0 = *(const float4*)(ap);
      float4 a1 = *(const float4*)(ap + 4);
      bf16x8 ahi, alo;
      split8(a0, a1, ahi, alo);

      const int bbase = (n0 + m) * 72 + ksub * 32 + quad * 8;
      bf16x8 bh = *(const bf16x8*)(vH + bbase);
      bf16x8 bl = *(const bf16x8*)(vL + bbase);

      acc = __builtin_amdgcn_mfma_f32_16x16x32_bf16(alo, bh, acc, 0, 0, 0);
      acc = __builtin_amdgcn_mfma_f32_16x16x32_bf16(ahi, bl, acc, 0, 0, 0);
      acc = __builtin_amdgcn_mfma_f32_16x16x32_bf16(ahi, bh, acc, 0, 0, 0);
      __syncthreads();
    }

    // ---- Phase 4c: pair-reduce K-halves (w & w+4 share a col-tile) --------
    float* fscr = (float*)aux;
    if (wave >= 4) {
#pragma unroll
      for (int r = 0; r < 4; ++r) fscr[(wave - 4) * 256 + lane * 4 + r] = acc[r];
    }
    __syncthreads();
    if (wave < 4) {
      float* oh = outp + (size_t)h * N * D;
#pragma unroll
      for (int r = 0; r < 4; ++r) {
        float s2 = acc[r] + fscr[wave * 256 + lane * 4 + r];
        oh[(size_t)(row0 + quad * 4 + r) * D + n0 + m] = s2 / rowsum[quad * 4 + r];
      }
    }
  }
}

// ---------------------------------------------------------------------------
extern "C" void kernel_launch(void* const* d_in, const int* in_sizes, int n_in,
                              void* d_out, int out_size, void* d_ws, size_t ws_size,
                              hipStream_t stream) {
  const float* q = (const float*)d_in[0];
  const float* k = (const float*)d_in[1];
  const float* v = (const float*)d_in[2];
  float* out = (float*)d_out;
  float* attn = out + (size_t)BH * N * D;  // attn_p region of d_out

  fused_attn<<<dim3(N / ROWS, BH), 512, 0, stream>>>(q, k, v, out, attn);
}

// Round 2
// 651.677 us; speedup vs baseline: 1.2868x; 1.2868x over previous
//
#include <hip/hip_runtime.h>

#define N 2048
#define D 64
#define BH 16
#define NWORDS 3126          // bitmap words over r in [0,100000]
#define ROWS 16              // score rows per block
#define SCP 2052             // score-row pitch in floats (+4 pad -> bank rotation)
#define AUXW (2 * NWORDS)    // 6252 words multi-purpose LDS (bitmaps / fallback staging / scratch)

typedef __bf16 bf16x8 __attribute__((ext_vector_type(8)));
typedef float f32x4 __attribute__((ext_vector_type(4)));
typedef unsigned short u16;

union Bf16x8U {
  bf16x8 v;
  __bf16 e[8];
  u16 us[8];
};

// Split 8 fp32 (two float4) into hi/lo bf16 fragments: f = hi + lo + O(2^-16 f)
static __device__ inline void split8(const float4& a, const float4& b,
                                     bf16x8& hi, bf16x8& lo) {
  float f[8] = {a.x, a.y, a.z, a.w, b.x, b.y, b.z, b.w};
  Bf16x8U h, l;
#pragma unroll
  for (int i = 0; i < 8; ++i) {
    __bf16 hb = (__bf16)f[i];
    h.e[i] = hb;
    l.e[i] = (__bf16)(f[i] - (float)hb);
  }
  hi = h.v;
  lo = l.v;
}

// ---------------------------------------------------------------------------
// Prep 1: q -> scaled hi/lo bf16 planes; k -> hi/lo bf16 planes (same layout).
// ---------------------------------------------------------------------------
__global__ __launch_bounds__(256) void prep_qk(
    const float* __restrict__ q, const float* __restrict__ k,
    u16* __restrict__ qhP, u16* __restrict__ qlP,
    u16* __restrict__ khP, u16* __restrict__ klP) {
  const size_t i = ((size_t)blockIdx.x * 256 + threadIdx.x) * 4;
  float4 qv = *(const float4*)(q + i);
  float4 kv = *(const float4*)(k + i);
  float fq[4] = {qv.x * 0.125f, qv.y * 0.125f, qv.z * 0.125f, qv.w * 0.125f};
  float fk[4] = {kv.x, kv.y, kv.z, kv.w};
  union { ushort4 v; u16 e[4]; } qh4, ql4, kh4, kl4;
#pragma unroll
  for (int j = 0; j < 4; ++j) {
    __bf16 qhb = (__bf16)fq[j];
    qh4.e[j] = __builtin_bit_cast(u16, qhb);
    ql4.e[j] = __builtin_bit_cast(u16, (__bf16)(fq[j] - (float)qhb));
    __bf16 khb = (__bf16)fk[j];
    kh4.e[j] = __builtin_bit_cast(u16, khb);
    kl4.e[j] = __builtin_bit_cast(u16, (__bf16)(fk[j] - (float)khb));
  }
  *(ushort4*)(qhP + i) = qh4.v;
  *(ushort4*)(qlP + i) = ql4.v;
  *(ushort4*)(khP + i) = kh4.v;
  *(ushort4*)(klP + i) = kl4.v;
}

// ---------------------------------------------------------------------------
// Prep 2: v[h][k][n] -> vT{h,l}[h][n][k] bf16 planes (transpose + split).
// Block (ktile, head), 256 thr: thread (n = t>>2, g = t&3) gathers 16 scalars
// down column n (64 B-coalesced across the 16 lanes sharing g/j), writes 32 B.
// ---------------------------------------------------------------------------
__global__ __launch_bounds__(256) void prep_v(
    const float* __restrict__ v, u16* __restrict__ vThP, u16* __restrict__ vTlP) {
  const int h = blockIdx.y;
  const int k0 = blockIdx.x * 64;
  const int t = threadIdx.x;
  const int n = t >> 2;
  const int g = t & 3;
  const float* vp = v + (size_t)h * N * D + (size_t)(k0 + g * 16) * D + n;
  union { uint4 u4[2]; u16 us[16]; } H, L;
#pragma unroll
  for (int j = 0; j < 16; ++j) {
    float f = vp[(size_t)j * D];
    __bf16 hb = (__bf16)f;
    H.us[j] = __builtin_bit_cast(u16, hb);
    L.us[j] = __builtin_bit_cast(u16, (__bf16)(f - (float)hb));
  }
  const size_t o = (size_t)h * D * N + (size_t)n * N + k0 + g * 16;
  *(uint4*)(vThP + o) = H.u4[0];
  *(uint4*)(vThP + o + 8) = H.u4[1];
  *(uint4*)(vTlP + o) = L.u4[0];
  *(uint4*)(vTlP + o + 8) = L.u4[1];
}

// ---------------------------------------------------------------------------
// Fused attention, plane-fed: one block owns 16 score rows in LDS.
// P1: QK^T from pre-split planes (no staging, no split VALU, no barrier).
// P2: row max. P3: exp/round/bitmap dedup-sum + attn_p store folded in.
// P4: PV streamed from transposed v planes — zero barriers, zero staging.
// ---------------------------------------------------------------------------
__global__ __launch_bounds__(512) void fused_attn_pl(
    const u16* __restrict__ qhP, const u16* __restrict__ qlP,
    const u16* __restrict__ khP, const u16* __restrict__ klP,
    const u16* __restrict__ vThP, const u16* __restrict__ vTlP,
    float* __restrict__ outp, float* __restrict__ attnp) {
  __shared__ float sc[ROWS * SCP];   // 131,328 B score tile
  __shared__ unsigned aux[AUXW];     // 25,008 B: P3 bitmaps / P4c scratch
  __shared__ float rowmax[ROWS];
  __shared__ float rowsum[ROWS];

  const int h = blockIdx.y;
  const int row0 = blockIdx.x * ROWS;
  const int t = threadIdx.x;
  const int wave = t >> 6;
  const int lane = t & 63;
  const int m = lane & 15;
  const int quad = lane >> 4;

  // ================= Phase 1: sc = (q/8) @ k^T from planes =================
  {
    const size_t hb = (size_t)h * N * D;
    const size_t qoff = hb + (size_t)(row0 + m) * D + quad * 8;
    bf16x8 ahi0 = *(const bf16x8*)(qhP + qoff);
    bf16x8 ahi1 = *(const bf16x8*)(qhP + qoff + 32);
    bf16x8 alo0 = *(const bf16x8*)(qlP + qoff);
    bf16x8 alo1 = *(const bf16x8*)(qlP + qoff + 32);

    const int colbase = wave * 256;  // wave covers 16 col-tiles
    const u16* khh = khP + hb;
    const u16* kll = klP + hb;
    size_t off = (size_t)(colbase + m) * D + quad * 8;
    bf16x8 bhi0 = *(const bf16x8*)(khh + off);
    bf16x8 bhi1 = *(const bf16x8*)(khh + off + 32);
    bf16x8 blo0 = *(const bf16x8*)(kll + off);
    bf16x8 blo1 = *(const bf16x8*)(kll + off + 32);
#pragma unroll
    for (int ct = 0; ct < 16; ++ct) {
      bf16x8 nhi0, nhi1, nlo0, nlo1;
      if (ct < 15) {  // 1-deep prefetch of next k col-tile
        const size_t noff = off + (size_t)16 * D;
        nhi0 = *(const bf16x8*)(khh + noff);
        nhi1 = *(const bf16x8*)(khh + noff + 32);
        nlo0 = *(const bf16x8*)(kll + noff);
        nlo1 = *(const bf16x8*)(kll + noff + 32);
      }
      f32x4 c = {0.f, 0.f, 0.f, 0.f};
      // same accumulation order as the verified kernels
      c = __builtin_amdgcn_mfma_f32_16x16x32_bf16(alo0, bhi0, c, 0, 0, 0);
      c = __builtin_amdgcn_mfma_f32_16x16x32_bf16(alo1, bhi1, c, 0, 0, 0);
      c = __builtin_amdgcn_mfma_f32_16x16x32_bf16(ahi0, blo0, c, 0, 0, 0);
      c = __builtin_amdgcn_mfma_f32_16x16x32_bf16(ahi1, blo1, c, 0, 0, 0);
      c = __builtin_amdgcn_mfma_f32_16x16x32_bf16(ahi0, bhi0, c, 0, 0, 0);
      c = __builtin_amdgcn_mfma_f32_16x16x32_bf16(ahi1, bhi1, c, 0, 0, 0);
      const int cb = colbase + ct * 16 + m;
#pragma unroll
      for (int r = 0; r < 4; ++r) sc[(quad * 4 + r) * SCP + cb] = c[r];
      bhi0 = nhi0; bhi1 = nhi1; blo0 = nlo0; blo1 = nlo1;
      off += (size_t)16 * D;
    }
  }
  __syncthreads();

  // ================= Phase 2: per-row max (wave w -> rows w, w+8) ==========
#pragma unroll
  for (int rr = 0; rr < 2; ++rr) {
    const int r = wave + rr * 8;
    const float* rowp = &sc[r * SCP];
    float mx = -3.4e38f;
#pragma unroll
    for (int i = 0; i < 8; ++i) {
      float4 vv = *(const float4*)&rowp[(lane + i * 64) * 4];
      mx = fmaxf(mx, fmaxf(fmaxf(vv.x, vv.y), fmaxf(vv.z, vv.w)));
    }
#pragma unroll
    for (int o = 32; o > 0; o >>= 1) mx = fmaxf(mx, __shfl_xor(mx, o, 64));
    if (lane == 0) rowmax[r] = mx;
  }
  __syncthreads();

  // ====== Phase 3: exp -> round -> bitmap dedup-sum + attn_p store =========
  {
    const int g = wave >> 2;   // waves 0-3 -> rows 0..7, waves 4-7 -> rows 8..15
    const int tt = t & 255;
    unsigned* bm = aux + g * NWORDS;
#pragma unroll 1
    for (int it = 0; it < 8; ++it) {
      const int r = it + g * 8;
      for (int i = tt; i < NWORDS; i += 256) bm[i] = 0u;
      if (tt == 0) rowsum[r] = 0.0f;
      __syncthreads();
      const float mrow = rowmax[r];
      float* rowp = &sc[r * SCP];
      float4 x0 = *(const float4*)&rowp[tt * 4];
      float4 x1 = *(const float4*)&rowp[1024 + tt * 4];
      float xs[8] = {x0.x, x0.y, x0.z, x0.w, x1.x, x1.y, x1.z, x1.w};
      float xr[8];
      float lsum = 0.0f;
#pragma unroll
      for (int j = 0; j < 8; ++j) {
        float ex = expf(xs[j] - mrow);           // <= 1.0
        float rf = rintf(ex * 100000.0f);        // round-half-even, exact in fp32
        float xv = rf / 100000.0f;               // match reference fp32 divide
        xr[j] = xv;
        int ri = (int)rf;                        // 0..100000
        unsigned mask = 1u << (ri & 31);
        unsigned old = atomicOr(&bm[ri >> 5], mask);
        if (!(old & mask)) lsum += xv;           // each distinct value once
      }
      // write rounded values back (PV consumes unnormalized xv from LDS)
      *(float4*)&rowp[tt * 4] = make_float4(xr[0], xr[1], xr[2], xr[3]);
      *(float4*)&rowp[1024 + tt * 4] = make_float4(xr[4], xr[5], xr[6], xr[7]);
#pragma unroll
      for (int o = 32; o > 0; o >>= 1) lsum += __shfl_xor(lsum, o, 64);
      if (lane == 0) atomicAdd(&rowsum[r], lsum);
      __syncthreads();
      // folded P4a: threads still hold xr[] -> normalize and store attn_p row
      const float total = rowsum[r];
      float4* dst = (float4*)(attnp + ((size_t)h * N + row0 + r) * N);
      dst[tt] = make_float4(xr[0] / total, xr[1] / total, xr[2] / total, xr[3] / total);
      dst[256 + tt] = make_float4(xr[4] / total, xr[5] / total, xr[6] / total, xr[7] / total);
    }
  }
  __syncthreads();  // other group's last row write-back must land before PV

  // ===== Phase 4: PV on unnormalized xv, B streamed from vT planes =========
  {
    const int ctn = wave & 3;          // col-tile of this wave
    const int ksub = wave >> 2;        // K-half
    const int n0 = ctn * 16;
    const u16* vhh = vThP + (size_t)h * D * N + (size_t)(n0 + m) * N;
    const u16* vll = vTlP + (size_t)h * D * N + (size_t)(n0 + m) * N;
    f32x4 acc = {0.f, 0.f, 0.f, 0.f};

    int kk = ksub * 32 + quad * 8;
    bf16x8 bh = *(const bf16x8*)(vhh + kk);
    bf16x8 bl = *(const bf16x8*)(vll + kk);
#pragma unroll 2
    for (int k0 = 0; k0 < N; k0 += 64) {
      bf16x8 nbh, nbl;
      if (k0 + 64 < N) {  // 1-deep prefetch (L2-resident)
        nbh = *(const bf16x8*)(vhh + kk + 64);
        nbl = *(const bf16x8*)(vll + kk + 64);
      }
      const float* ap = &sc[(size_t)m * SCP + k0 + ksub * 32 + quad * 8];
      float4 a0 = *(const float4*)(ap);
      float4 a1 = *(const float4*)(ap + 4);
      bf16x8 ahi, alo;
      split8(a0, a1, ahi, alo);
      acc = __builtin_amdgcn_mfma_f32_16x16x32_bf16(alo, bh, acc, 0, 0, 0);
      acc = __builtin_amdgcn_mfma_f32_16x16x32_bf16(ahi, bl, acc, 0, 0, 0);
      acc = __builtin_amdgcn_mfma_f32_16x16x32_bf16(ahi, bh, acc, 0, 0, 0);
      bh = nbh; bl = nbl;
      kk += 64;
    }

    // ---- pair-reduce K-halves (w & w+4 share a col-tile) ------------------
    float* fscr = (float*)aux;
    if (wave >= 4) {
#pragma unroll
      for (int r = 0; r < 4; ++r) fscr[(wave - 4) * 256 + lane * 4 + r] = acc[r];
    }
    __syncthreads();
    if (wave < 4) {
      float* oh = outp + (size_t)h * N * D;
#pragma unroll
      for (int r = 0; r < 4; ++r) {
        float s2 = acc[r] + fscr[wave * 256 + lane * 4 + r];
        oh[(size_t)(row0 + quad * 4 + r) * D + n0 + m] = s2 / rowsum[quad * 4 + r];
      }
    }
  }
}

// ---------------------------------------------------------------------------
// Fallback (verified round-1 kernel, used only if ws_size < 24 MB).
// ---------------------------------------------------------------------------
__global__ __launch_bounds__(512) void fused_attn_fb(
    const float* __restrict__ q, const float* __restrict__ k,
    const float* __restrict__ v, float* __restrict__ outp,
    float* __restrict__ attnp) {
  __shared__ float sc[ROWS * SCP];
  __shared__ unsigned aux[AUXW];
  __shared__ float rowmax[ROWS];
  __shared__ float rowsum[ROWS];

  const int h = blockIdx.y;
  const int row0 = blockIdx.x * ROWS;
  const float* qh = q + (size_t)h * N * D;
  const float* kh = k + (size_t)h * N * D;
  const float* vh = v + (size_t)h * N * D;

  const int t = threadIdx.x;
  const int wave = t >> 6;
  const int lane = t & 63;
  const int m = lane & 15;
  const int quad = lane >> 4;

  {
    float* qlds = (float*)aux;
    if (t < 256) {
      const int qr = t >> 4;
      const int qc = (t & 15) * 4;
      float4 vv = *(const float4*)(qh + (size_t)(row0 + qr) * D + qc);
      vv.x *= 0.125f; vv.y *= 0.125f; vv.z *= 0.125f; vv.w *= 0.125f;
      *(float4*)&qlds[qr * 68 + qc] = vv;
    }
    __syncthreads();

    bf16x8 ahi0, alo0, ahi1, alo1;
    {
      const float* qp = &qlds[m * 68 + quad * 8];
      float4 a00 = *(const float4*)(qp);
      float4 a01 = *(const float4*)(qp + 4);
      float4 a10 = *(const float4*)(qp + 32);
      float4 a11 = *(const float4*)(qp + 36);
      split8(a00, a01, ahi0, alo0);
      split8(a10, a11, ahi1, alo1);
    }

    const int colbase = wave * 256;
    float4 c0, c1, c2, c3, p0, p1, p2, p3;
    {
      const float* kr = kh + (size_t)(colbase + m) * D + quad * 8;
      c0 = *(const float4*)(kr);
      c1 = *(const float4*)(kr + 4);
      c2 = *(const float4*)(kr + 32);
      c3 = *(const float4*)(kr + 36);
    }
#pragma unroll
    for (int ct = 0; ct < 16; ++ct) {
      if (ct < 15) {
        const float* kr = kh + (size_t)(colbase + (ct + 1) * 16 + m) * D + quad * 8;
        p0 = *(const float4*)(kr);
        p1 = *(const float4*)(kr + 4);
        p2 = *(const float4*)(kr + 32);
        p3 = *(const float4*)(kr + 36);
      }
      bf16x8 bhi0, blo0, bhi1, blo1;
      split8(c0, c1, bhi0, blo0);
      split8(c2, c3, bhi1, blo1);
      f32x4 acc = {0.f, 0.f, 0.f, 0.f};
      acc = __builtin_amdgcn_mfma_f32_16x16x32_bf16(alo0, bhi0, acc, 0, 0, 0);
      acc = __builtin_amdgcn_mfma_f32_16x16x32_bf16(alo1, bhi1, acc, 0, 0, 0);
      acc = __builtin_amdgcn_mfma_f32_16x16x32_bf16(ahi0, blo0, acc, 0, 0, 0);
      acc = __builtin_amdgcn_mfma_f32_16x16x32_bf16(ahi1, blo1, acc, 0, 0, 0);
      acc = __builtin_amdgcn_mfma_f32_16x16x32_bf16(ahi0, bhi0, acc, 0, 0, 0);
      acc = __builtin_amdgcn_mfma_f32_16x16x32_bf16(ahi1, bhi1, acc, 0, 0, 0);
      const int cb = colbase + ct * 16 + m;
#pragma unroll
      for (int r = 0; r < 4; ++r) sc[(quad * 4 + r) * SCP + cb] = acc[r];
      c0 = p0; c1 = p1; c2 = p2; c3 = p3;
    }
  }
  __syncthreads();

#pragma unroll
  for (int rr = 0; rr < 2; ++rr) {
    const int r = wave + rr * 8;
    const float* rowp = &sc[r * SCP];
    float mx = -3.4e38f;
#pragma unroll
    for (int i = 0; i < 8; ++i) {
      float4 vv = *(const float4*)&rowp[(lane + i * 64) * 4];
      mx = fmaxf(mx, fmaxf(fmaxf(vv.x, vv.y), fmaxf(vv.z, vv.w)));
    }
#pragma unroll
    for (int o = 32; o > 0; o >>= 1) mx = fmaxf(mx, __shfl_xor(mx, o, 64));
    if (lane == 0) rowmax[r] = mx;
  }
  __syncthreads();

  {
    const int g = wave >> 2;
    const int tt = t & 255;
    unsigned* bm = aux + g * NWORDS;
#pragma unroll 1
    for (int it = 0; it < 8; ++it) {
      const int r = it + g * 8;
      for (int i = tt; i < NWORDS; i += 256) bm[i] = 0u;
      if (tt == 0) rowsum[r] = 0.0f;
      __syncthreads();
      const float mrow = rowmax[r];
      float* rowp = &sc[r * SCP];
      float4 x0 = *(const float4*)&rowp[tt * 4];
      float4 x1 = *(const float4*)&rowp[1024 + tt * 4];
      float xs[8] = {x0.x, x0.y, x0.z, x0.w, x1.x, x1.y, x1.z, x1.w};
      float xr[8];
      float lsum = 0.0f;
#pragma unroll
      for (int j = 0; j < 8; ++j) {
        float ex = expf(xs[j] - mrow);
        float rf = rintf(ex * 100000.0f);
        float xv = rf / 100000.0f;
        xr[j] = xv;
        int ri = (int)rf;
        unsigned mask = 1u << (ri & 31);
        unsigned old = atomicOr(&bm[ri >> 5], mask);
        if (!(old & mask)) lsum += xv;
      }
      *(float4*)&rowp[tt * 4] = make_float4(xr[0], xr[1], xr[2], xr[3]);
      *(float4*)&rowp[1024 + tt * 4] = make_float4(xr[4], xr[5], xr[6], xr[7]);
#pragma unroll
      for (int o = 32; o > 0; o >>= 1) lsum += __shfl_xor(lsum, o, 64);
      if (lane == 0) atomicAdd(&rowsum[r], lsum);
      __syncthreads();
      const float total = rowsum[r];
      float4* dst = (float4*)(attnp + ((size_t)h * N + row0 + r) * N);
      dst[tt] = make_float4(xr[0] / total, xr[1] / total, xr[2] / total, xr[3] / total);
      dst[256 + tt] = make_float4(xr[4] / total, xr[5] / total, xr[6] / total, xr[7] / total);
    }
  }
  __syncthreads();

  {
    unsigned* vpack = aux;  // [64][65] packed (hi<<16)|lo
    const int skk = t >> 4;
    const int snn = (t & 15) * 4;
    const int ctn = wave & 3;
    const int ksub = wave >> 2;
    const int n0 = ctn * 16;
    f32x4 acc = {0.f, 0.f, 0.f, 0.f};

#pragma unroll 1
    for (int k0 = 0; k0 < N; k0 += 64) {
      __syncthreads();
#pragma unroll
      for (int i = 0; i < 2; ++i) {
        int kk = skk + i * 32;
        float4 vv = *(const float4*)(vh + (size_t)(k0 + kk) * D + snn);
        float f[4] = {vv.x, vv.y, vv.z, vv.w};
#pragma unroll
        for (int j = 0; j < 4; ++j) {
          __bf16 hb = (__bf16)f[j];
          __bf16 lb = (__bf16)(f[j] - (float)hb);
          unsigned hu = (unsigned)__builtin_bit_cast(u16, hb);
          unsigned lu = (unsigned)__builtin_bit_cast(u16, lb);
          vpack[(size_t)kk * 65 + snn + j] = (hu << 16) | lu;
        }
      }
      __syncthreads();

      const float* ap = &sc[(size_t)m * SCP + k0 + ksub * 32 + quad * 8];
      float4 a0 = *(const float4*)(ap);
      float4 a1 = *(const float4*)(ap + 4);
      bf16x8 ahi, alo;
      split8(a0, a1, ahi, alo);

      Bf16x8U bhh, bll;
#pragma unroll
      for (int j = 0; j < 8; ++j) {
        unsigned u = vpack[(size_t)(ksub * 32 + quad * 8 + j) * 65 + n0 + m];
        bhh.us[j] = (u16)(u >> 16);
        bll.us[j] = (u16)(u & 0xffffu);
      }
      acc = __builtin_amdgcn_mfma_f32_16x16x32_bf16(alo, bhh.v, acc, 0, 0, 0);
      acc = __builtin_amdgcn_mfma_f32_16x16x32_bf16(ahi, bll.v, acc, 0, 0, 0);
      acc = __builtin_amdgcn_mfma_f32_16x16x32_bf16(ahi, bhh.v, acc, 0, 0, 0);
    }
    __syncthreads();

    float* fscr = (float*)aux;
    if (wave >= 4) {
#pragma unroll
      for (int r = 0; r < 4; ++r) fscr[(wave - 4) * 256 + lane * 4 + r] = acc[r];
    }
    __syncthreads();
    if (wave < 4) {
      float* oh = outp + (size_t)h * N * D;
#pragma unroll
      for (int r = 0; r < 4; ++r) {
        float s2 = acc[r] + fscr[wave * 256 + lane * 4 + r];
        oh[(size_t)(row0 + quad * 4 + r) * D + n0 + m] = s2 / rowsum[quad * 4 + r];
      }
    }
  }
}

// ---------------------------------------------------------------------------
extern "C" void kernel_launch(void* const* d_in, const int* in_sizes, int n_in,
                              void* d_out, int out_size, void* d_ws, size_t ws_size,
                              hipStream_t stream) {
  const float* q = (const float*)d_in[0];
  const float* k = (const float*)d_in[1];
  const float* v = (const float*)d_in[2];
  float* out = (float*)d_out;
  float* attn = out + (size_t)BH * N * D;  // attn_p region of d_out

  const size_t PLANE = (size_t)BH * N * D;  // 2,097,152 elems
  const size_t need = PLANE * 6 * sizeof(u16);  // 24 MB
  if (ws_size >= need && d_ws != nullptr) {
    u16* base = (u16*)d_ws;
    u16* qhP = base;
    u16* qlP = base + PLANE;
    u16* khP = base + 2 * PLANE;
    u16* klP = base + 3 * PLANE;
    u16* vThP = base + 4 * PLANE;
    u16* vTlP = base + 5 * PLANE;
    prep_qk<<<dim3((unsigned)(PLANE / 1024)), 256, 0, stream>>>(q, k, qhP, qlP, khP, klP);
    prep_v<<<dim3(N / 64, BH), 256, 0, stream>>>(v, vThP, vTlP);
    fused_attn_pl<<<dim3(N / ROWS, BH), 512, 0, stream>>>(qhP, qlP, khP, klP, vThP, vTlP, out, attn);
  } else {
    fused_attn_fb<<<dim3(N / ROWS, BH), 512, 0, stream>>>(q, k, v, out, attn);
  }
}

// Round 3
// 638.066 us; speedup vs baseline: 1.3142x; 1.0213x over previous
//
#include <hip/hip_runtime.h>

#define N 2048
#define D 64
#define BH 16
#define NWORDS 3126          // bitmap words over r in [0,100000]
#define ROWS 16              // score rows per block
#define SCP 2052             // score-row pitch in floats (+4 pad -> bank rotation)
#define AUXW (2 * NWORDS)    // 6252 words multi-purpose LDS (bitmaps / scratch)

typedef __bf16 bf16x8 __attribute__((ext_vector_type(8)));
typedef float f32x4 __attribute__((ext_vector_type(4)));
typedef unsigned short u16;

union Bf16x8U {
  bf16x8 v;
  __bf16 e[8];
  u16 us[8];
};

// Split 8 fp32 (two float4) into hi/lo bf16 fragments: f = hi + lo + O(2^-16 f)
static __device__ inline void split8(const float4& a, const float4& b,
                                     bf16x8& hi, bf16x8& lo) {
  float f[8] = {a.x, a.y, a.z, a.w, b.x, b.y, b.z, b.w};
  Bf16x8U h, l;
#pragma unroll
  for (int i = 0; i < 8; ++i) {
    __bf16 hb = (__bf16)f[i];
    h.e[i] = hb;
    l.e[i] = (__bf16)(f[i] - (float)hb);
  }
  hi = h.v;
  lo = l.v;
}

// ---------------------------------------------------------------------------
// Prep 1: q -> scaled hi/lo bf16 planes; k -> hi/lo bf16 planes (same layout).
// ---------------------------------------------------------------------------
__global__ __launch_bounds__(256) void prep_qk(
    const float* __restrict__ q, const float* __restrict__ k,
    u16* __restrict__ qhP, u16* __restrict__ qlP,
    u16* __restrict__ khP, u16* __restrict__ klP) {
  const size_t i = ((size_t)blockIdx.x * 256 + threadIdx.x) * 4;
  float4 qv = *(const float4*)(q + i);
  float4 kv = *(const float4*)(k + i);
  float fq[4] = {qv.x * 0.125f, qv.y * 0.125f, qv.z * 0.125f, qv.w * 0.125f};
  float fk[4] = {kv.x, kv.y, kv.z, kv.w};
  union { ushort4 v; u16 e[4]; } qh4, ql4, kh4, kl4;
#pragma unroll
  for (int j = 0; j < 4; ++j) {
    __bf16 qhb = (__bf16)fq[j];
    qh4.e[j] = __builtin_bit_cast(u16, qhb);
    ql4.e[j] = __builtin_bit_cast(u16, (__bf16)(fq[j] - (float)qhb));
    __bf16 khb = (__bf16)fk[j];
    kh4.e[j] = __builtin_bit_cast(u16, khb);
    kl4.e[j] = __builtin_bit_cast(u16, (__bf16)(fk[j] - (float)khb));
  }
  *(ushort4*)(qhP + i) = qh4.v;
  *(ushort4*)(qlP + i) = ql4.v;
  *(ushort4*)(khP + i) = kh4.v;
  *(ushort4*)(klP + i) = kl4.v;
}

// ---------------------------------------------------------------------------
// Prep 2: v[h][k][n] -> vT{h,l}[h][n][k] bf16 planes (transpose + split).
// ---------------------------------------------------------------------------
__global__ __launch_bounds__(256) void prep_v(
    const float* __restrict__ v, u16* __restrict__ vThP, u16* __restrict__ vTlP) {
  const int h = blockIdx.y;
  const int k0 = blockIdx.x * 64;
  const int t = threadIdx.x;
  const int n = t >> 2;
  const int g = t & 3;
  const float* vp = v + (size_t)h * N * D + (size_t)(k0 + g * 16) * D + n;
  union { uint4 u4[2]; u16 us[16]; } H, L;
#pragma unroll
  for (int j = 0; j < 16; ++j) {
    float f = vp[(size_t)j * D];
    __bf16 hb = (__bf16)f;
    H.us[j] = __builtin_bit_cast(u16, hb);
    L.us[j] = __builtin_bit_cast(u16, (__bf16)(f - (float)hb));
  }
  const size_t o = (size_t)h * D * N + (size_t)n * N + k0 + g * 16;
  *(uint4*)(vThP + o) = H.u4[0];
  *(uint4*)(vThP + o + 8) = H.u4[1];
  *(uint4*)(vTlP + o) = L.u4[0];
  *(uint4*)(vTlP + o + 8) = L.u4[1];
}

// ---------------------------------------------------------------------------
// Fused attention, plane-fed, 1024 threads (16 waves -> 4 waves/SIMD).
// Same LDS structure as the verified 512-thr version; work split finer so
// each SIMD has 4 resident waves to hide exp/atomic/LDS/L2 latency.
// ---------------------------------------------------------------------------
__global__ __launch_bounds__(1024) void fused_attn_pl(
    const u16* __restrict__ qhP, const u16* __restrict__ qlP,
    const u16* __restrict__ khP, const u16* __restrict__ klP,
    const u16* __restrict__ vThP, const u16* __restrict__ vTlP,
    float* __restrict__ outp, float* __restrict__ attnp) {
  __shared__ float sc[ROWS * SCP];   // 131,328 B score tile
  __shared__ unsigned aux[AUXW];     // 25,008 B: P3 bitmaps / P4 scratch
  __shared__ float rowmax[ROWS];
  __shared__ float rowsum[ROWS];

  const int h = blockIdx.y;
  const int row0 = blockIdx.x * ROWS;
  const int t = threadIdx.x;
  const int wave = t >> 6;       // 0..15
  const int lane = t & 63;
  const int m = lane & 15;
  const int quad = lane >> 4;

  // ================= Phase 1: sc = (q/8) @ k^T from planes =================
  {
    const size_t hb = (size_t)h * N * D;
    const size_t qoff = hb + (size_t)(row0 + m) * D + quad * 8;
    bf16x8 ahi0 = *(const bf16x8*)(qhP + qoff);
    bf16x8 ahi1 = *(const bf16x8*)(qhP + qoff + 32);
    bf16x8 alo0 = *(const bf16x8*)(qlP + qoff);
    bf16x8 alo1 = *(const bf16x8*)(qlP + qoff + 32);

    const int colbase = wave * 128;  // wave covers 8 col-tiles
    const u16* khh = khP + hb;
    const u16* kll = klP + hb;
    size_t off = (size_t)(colbase + m) * D + quad * 8;
    bf16x8 bhi0 = *(const bf16x8*)(khh + off);
    bf16x8 bhi1 = *(const bf16x8*)(khh + off + 32);
    bf16x8 blo0 = *(const bf16x8*)(kll + off);
    bf16x8 blo1 = *(const bf16x8*)(kll + off + 32);
#pragma unroll
    for (int ct = 0; ct < 8; ++ct) {
      bf16x8 nhi0, nhi1, nlo0, nlo1;
      if (ct < 7) {  // 1-deep prefetch of next k col-tile
        const size_t noff = off + (size_t)16 * D;
        nhi0 = *(const bf16x8*)(khh + noff);
        nhi1 = *(const bf16x8*)(khh + noff + 32);
        nlo0 = *(const bf16x8*)(kll + noff);
        nlo1 = *(const bf16x8*)(kll + noff + 32);
      }
      f32x4 c = {0.f, 0.f, 0.f, 0.f};
      // same accumulation order as the verified kernels
      c = __builtin_amdgcn_mfma_f32_16x16x32_bf16(alo0, bhi0, c, 0, 0, 0);
      c = __builtin_amdgcn_mfma_f32_16x16x32_bf16(alo1, bhi1, c, 0, 0, 0);
      c = __builtin_amdgcn_mfma_f32_16x16x32_bf16(ahi0, blo0, c, 0, 0, 0);
      c = __builtin_amdgcn_mfma_f32_16x16x32_bf16(ahi1, blo1, c, 0, 0, 0);
      c = __builtin_amdgcn_mfma_f32_16x16x32_bf16(ahi0, bhi0, c, 0, 0, 0);
      c = __builtin_amdgcn_mfma_f32_16x16x32_bf16(ahi1, bhi1, c, 0, 0, 0);
      const int cb = colbase + ct * 16 + m;
#pragma unroll
      for (int r = 0; r < 4; ++r) sc[(quad * 4 + r) * SCP + cb] = c[r];
      bhi0 = nhi0; bhi1 = nhi1; blo0 = nlo0; blo1 = nlo1;
      off += (size_t)16 * D;
    }
  }
  __syncthreads();

  // ================= Phase 2: per-row max (wave w -> row w) ================
  {
    const int r = wave;
    const float* rowp = &sc[r * SCP];
    float mx = -3.4e38f;
#pragma unroll
    for (int i = 0; i < 8; ++i) {
      float4 vv = *(const float4*)&rowp[(lane + i * 64) * 4];
      mx = fmaxf(mx, fmaxf(fmaxf(vv.x, vv.y), fmaxf(vv.z, vv.w)));
    }
#pragma unroll
    for (int o = 32; o > 0; o >>= 1) mx = fmaxf(mx, __shfl_xor(mx, o, 64));
    if (lane == 0) rowmax[r] = mx;
  }
  __syncthreads();

  // ====== Phase 3: exp -> round -> bitmap dedup-sum + attn_p store =========
  // 2 rows concurrently, 512 threads (8 waves) per row, 4 elems/thread.
  {
    const int g = wave >> 3;   // waves 0-7 -> rows 0..7, waves 8-15 -> rows 8..15
    const int tt = t & 511;
    unsigned* bm = aux + g * NWORDS;
#pragma unroll 1
    for (int it = 0; it < 8; ++it) {
      const int r = it + g * 8;
      for (int i = tt; i < NWORDS; i += 512) bm[i] = 0u;
      if (tt == 0) rowsum[r] = 0.0f;
      __syncthreads();
      const float mrow = rowmax[r];
      float* rowp = &sc[r * SCP];
      float4 x0 = *(const float4*)&rowp[tt * 4];
      float xs[4] = {x0.x, x0.y, x0.z, x0.w};
      float xr[4];
      float lsum = 0.0f;
#pragma unroll
      for (int j = 0; j < 4; ++j) {
        float ex = expf(xs[j] - mrow);           // <= 1.0
        float rf = rintf(ex * 100000.0f);        // round-half-even, exact in fp32
        float xv = rf / 100000.0f;               // match reference fp32 divide
        xr[j] = xv;
        int ri = (int)rf;                        // 0..100000
        unsigned mask = 1u << (ri & 31);
        unsigned old = atomicOr(&bm[ri >> 5], mask);
        if (!(old & mask)) lsum += xv;           // each distinct value once
      }
      // write rounded values back (PV consumes unnormalized xv from LDS)
      *(float4*)&rowp[tt * 4] = make_float4(xr[0], xr[1], xr[2], xr[3]);
#pragma unroll
      for (int o = 32; o > 0; o >>= 1) lsum += __shfl_xor(lsum, o, 64);
      if (lane == 0) atomicAdd(&rowsum[r], lsum);
      __syncthreads();
      // folded P4a: threads still hold xr[] -> normalize and store attn_p row
      const float total = rowsum[r];
      float4* dst = (float4*)(attnp + ((size_t)h * N + row0 + r) * N);
      dst[tt] = make_float4(xr[0] / total, xr[1] / total, xr[2] / total, xr[3] / total);
    }
  }
  __syncthreads();  // all rows final before PV

  // ===== Phase 4: PV on unnormalized xv, B streamed from vT planes =========
  // wave = ksub*4 + ctn: ctn = col-tile (16 cols), ksub = K-quarter (512).
  {
    const int ctn = wave & 3;
    const int ksub = wave >> 2;        // 0..3
    const int n0 = ctn * 16;
    const u16* vhh = vThP + (size_t)h * D * N + (size_t)(n0 + m) * N;
    const u16* vll = vTlP + (size_t)h * D * N + (size_t)(n0 + m) * N;
    f32x4 acc = {0.f, 0.f, 0.f, 0.f};

    const int kbeg = ksub * 512;
    int kk = kbeg + quad * 8;
    bf16x8 bh = *(const bf16x8*)(vhh + kk);
    bf16x8 bl = *(const bf16x8*)(vll + kk);
#pragma unroll 2
    for (int k0 = kbeg; k0 < kbeg + 512; k0 += 32) {
      bf16x8 nbh, nbl;
      if (k0 + 32 < kbeg + 512) {  // 1-deep prefetch (L2-resident)
        nbh = *(const bf16x8*)(vhh + kk + 32);
        nbl = *(const bf16x8*)(vll + kk + 32);
      }
      const float* ap = &sc[(size_t)m * SCP + k0 + quad * 8];
      float4 a0 = *(const float4*)(ap);
      float4 a1 = *(const float4*)(ap + 4);
      bf16x8 ahi, alo;
      split8(a0, a1, ahi, alo);
      acc = __builtin_amdgcn_mfma_f32_16x16x32_bf16(alo, bh, acc, 0, 0, 0);
      acc = __builtin_amdgcn_mfma_f32_16x16x32_bf16(ahi, bl, acc, 0, 0, 0);
      acc = __builtin_amdgcn_mfma_f32_16x16x32_bf16(ahi, bh, acc, 0, 0, 0);
      bh = nbh; bl = nbl;
      kk += 32;
    }

    // ---- reduce 4 K-quarter partials per col-tile -------------------------
    float* fscr = (float*)aux;   // 12 x 256 floats
    if (ksub > 0) {
#pragma unroll
      for (int r = 0; r < 4; ++r)
        fscr[((ksub - 1) * 4 + ctn) * 256 + lane * 4 + r] = acc[r];
    }
    __syncthreads();
    if (ksub == 0) {
      float* oh = outp + (size_t)h * N * D;
#pragma unroll
      for (int r = 0; r < 4; ++r) {
        float s2 = acc[r]
                 + fscr[(0 * 4 + ctn) * 256 + lane * 4 + r]
                 + fscr[(1 * 4 + ctn) * 256 + lane * 4 + r]
                 + fscr[(2 * 4 + ctn) * 256 + lane * 4 + r];
        oh[(size_t)(row0 + quad * 4 + r) * D + n0 + m] = s2 / rowsum[quad * 4 + r];
      }
    }
  }
}

// ---------------------------------------------------------------------------
// Fallback (verified round-1 kernel, used only if ws_size < 24 MB).
// ---------------------------------------------------------------------------
__global__ __launch_bounds__(512) void fused_attn_fb(
    const float* __restrict__ q, const float* __restrict__ k,
    const float* __restrict__ v, float* __restrict__ outp,
    float* __restrict__ attnp) {
  __shared__ float sc[ROWS * SCP];
  __shared__ unsigned aux[AUXW];
  __shared__ float rowmax[ROWS];
  __shared__ float rowsum[ROWS];

  const int h = blockIdx.y;
  const int row0 = blockIdx.x * ROWS;
  const float* qh = q + (size_t)h * N * D;
  const float* kh = k + (size_t)h * N * D;
  const float* vh = v + (size_t)h * N * D;

  const int t = threadIdx.x;
  const int wave = t >> 6;
  const int lane = t & 63;
  const int m = lane & 15;
  const int quad = lane >> 4;

  {
    float* qlds = (float*)aux;
    if (t < 256) {
      const int qr = t >> 4;
      const int qc = (t & 15) * 4;
      float4 vv = *(const float4*)(qh + (size_t)(row0 + qr) * D + qc);
      vv.x *= 0.125f; vv.y *= 0.125f; vv.z *= 0.125f; vv.w *= 0.125f;
      *(float4*)&qlds[qr * 68 + qc] = vv;
    }
    __syncthreads();

    bf16x8 ahi0, alo0, ahi1, alo1;
    {
      const float* qp = &qlds[m * 68 + quad * 8];
      float4 a00 = *(const float4*)(qp);
      float4 a01 = *(const float4*)(qp + 4);
      float4 a10 = *(const float4*)(qp + 32);
      float4 a11 = *(const float4*)(qp + 36);
      split8(a00, a01, ahi0, alo0);
      split8(a10, a11, ahi1, alo1);
    }

    const int colbase = wave * 256;
    float4 c0, c1, c2, c3, p0, p1, p2, p3;
    {
      const float* kr = kh + (size_t)(colbase + m) * D + quad * 8;
      c0 = *(const float4*)(kr);
      c1 = *(const float4*)(kr + 4);
      c2 = *(const float4*)(kr + 32);
      c3 = *(const float4*)(kr + 36);
    }
#pragma unroll
    for (int ct = 0; ct < 16; ++ct) {
      if (ct < 15) {
        const float* kr = kh + (size_t)(colbase + (ct + 1) * 16 + m) * D + quad * 8;
        p0 = *(const float4*)(kr);
        p1 = *(const float4*)(kr + 4);
        p2 = *(const float4*)(kr + 32);
        p3 = *(const float4*)(kr + 36);
      }
      bf16x8 bhi0, blo0, bhi1, blo1;
      split8(c0, c1, bhi0, blo0);
      split8(c2, c3, bhi1, blo1);
      f32x4 acc = {0.f, 0.f, 0.f, 0.f};
      acc = __builtin_amdgcn_mfma_f32_16x16x32_bf16(alo0, bhi0, acc, 0, 0, 0);
      acc = __builtin_amdgcn_mfma_f32_16x16x32_bf16(alo1, bhi1, acc, 0, 0, 0);
      acc = __builtin_amdgcn_mfma_f32_16x16x32_bf16(ahi0, blo0, acc, 0, 0, 0);
      acc = __builtin_amdgcn_mfma_f32_16x16x32_bf16(ahi1, blo1, acc, 0, 0, 0);
      acc = __builtin_amdgcn_mfma_f32_16x16x32_bf16(ahi0, bhi0, acc, 0, 0, 0);
      acc = __builtin_amdgcn_mfma_f32_16x16x32_bf16(ahi1, bhi1, acc, 0, 0, 0);
      const int cb = colbase + ct * 16 + m;
#pragma unroll
      for (int r = 0; r < 4; ++r) sc[(quad * 4 + r) * SCP + cb] = acc[r];
      c0 = p0; c1 = p1; c2 = p2; c3 = p3;
    }
  }
  __syncthreads();

#pragma unroll
  for (int rr = 0; rr < 2; ++rr) {
    const int r = wave + rr * 8;
    const float* rowp = &sc[r * SCP];
    float mx = -3.4e38f;
#pragma unroll
    for (int i = 0; i < 8; ++i) {
      float4 vv = *(const float4*)&rowp[(lane + i * 64) * 4];
      mx = fmaxf(mx, fmaxf(fmaxf(vv.x, vv.y), fmaxf(vv.z, vv.w)));
    }
#pragma unroll
    for (int o = 32; o > 0; o >>= 1) mx = fmaxf(mx, __shfl_xor(mx, o, 64));
    if (lane == 0) rowmax[r] = mx;
  }
  __syncthreads();

  {
    const int g = wave >> 2;
    const int tt = t & 255;
    unsigned* bm = aux + g * NWORDS;
#pragma unroll 1
    for (int it = 0; it < 8; ++it) {
      const int r = it + g * 8;
      for (int i = tt; i < NWORDS; i += 256) bm[i] = 0u;
      if (tt == 0) rowsum[r] = 0.0f;
      __syncthreads();
      const float mrow = rowmax[r];
      float* rowp = &sc[r * SCP];
      float4 x0 = *(const float4*)&rowp[tt * 4];
      float4 x1 = *(const float4*)&rowp[1024 + tt * 4];
      float xs[8] = {x0.x, x0.y, x0.z, x0.w, x1.x, x1.y, x1.z, x1.w};
      float xr[8];
      float lsum = 0.0f;
#pragma unroll
      for (int j = 0; j < 8; ++j) {
        float ex = expf(xs[j] - mrow);
        float rf = rintf(ex * 100000.0f);
        float xv = rf / 100000.0f;
        xr[j] = xv;
        int ri = (int)rf;
        unsigned mask = 1u << (ri & 31);
        unsigned old = atomicOr(&bm[ri >> 5], mask);
        if (!(old & mask)) lsum += xv;
      }
      *(float4*)&rowp[tt * 4] = make_float4(xr[0], xr[1], xr[2], xr[3]);
      *(float4*)&rowp[1024 + tt * 4] = make_float4(xr[4], xr[5], xr[6], xr[7]);
#pragma unroll
      for (int o = 32; o > 0; o >>= 1) lsum += __shfl_xor(lsum, o, 64);
      if (lane == 0) atomicAdd(&rowsum[r], lsum);
      __syncthreads();
      const float total = rowsum[r];
      float4* dst = (float4*)(attnp + ((size_t)h * N + row0 + r) * N);
      dst[tt] = make_float4(xr[0] / total, xr[1] / total, xr[2] / total, xr[3] / total);
      dst[256 + tt] = make_float4(xr[4] / total, xr[5] / total, xr[6] / total, xr[7] / total);
    }
  }
  __syncthreads();

  {
    unsigned* vpack = aux;  // [64][65] packed (hi<<16)|lo
    const int skk = t >> 4;
    const int snn = (t & 15) * 4;
    const int ctn = wave & 3;
    const int ksub = wave >> 2;
    const int n0 = ctn * 16;
    f32x4 acc = {0.f, 0.f, 0.f, 0.f};

#pragma unroll 1
    for (int k0 = 0; k0 < N; k0 += 64) {
      __syncthreads();
#pragma unroll
      for (int i = 0; i < 2; ++i) {
        int kk = skk + i * 32;
        float4 vv = *(const float4*)(vh + (size_t)(k0 + kk) * D + snn);
        float f[4] = {vv.x, vv.y, vv.z, vv.w};
#pragma unroll
        for (int j = 0; j < 4; ++j) {
          __bf16 hb = (__bf16)f[j];
          __bf16 lb = (__bf16)(f[j] - (float)hb);
          unsigned hu = (unsigned)__builtin_bit_cast(u16, hb);
          unsigned lu = (unsigned)__builtin_bit_cast(u16, lb);
          vpack[(size_t)kk * 65 + snn + j] = (hu << 16) | lu;
        }
      }
      __syncthreads();

      const float* ap = &sc[(size_t)m * SCP + k0 + ksub * 32 + quad * 8];
      float4 a0 = *(const float4*)(ap);
      float4 a1 = *(const float4*)(ap + 4);
      bf16x8 ahi, alo;
      split8(a0, a1, ahi, alo);

      Bf16x8U bhh, bll;
#pragma unroll
      for (int j = 0; j < 8; ++j) {
        unsigned u = vpack[(size_t)(ksub * 32 + quad * 8 + j) * 65 + n0 + m];
        bhh.us[j] = (u16)(u >> 16);
        bll.us[j] = (u16)(u & 0xffffu);
      }
      acc = __builtin_amdgcn_mfma_f32_16x16x32_bf16(alo, bhh.v, acc, 0, 0, 0);
      acc = __builtin_amdgcn_mfma_f32_16x16x32_bf16(ahi, bll.v, acc, 0, 0, 0);
      acc = __builtin_amdgcn_mfma_f32_16x16x32_bf16(ahi, bhh.v, acc, 0, 0, 0);
    }
    __syncthreads();

    float* fscr = (float*)aux;
    if (wave >= 4) {
#pragma unroll
      for (int r = 0; r < 4; ++r) fscr[(wave - 4) * 256 + lane * 4 + r] = acc[r];
    }
    __syncthreads();
    if (wave < 4) {
      float* oh = outp + (size_t)h * N * D;
#pragma unroll
      for (int r = 0; r < 4; ++r) {
        float s2 = acc[r] + fscr[wave * 256 + lane * 4 + r];
        oh[(size_t)(row0 + quad * 4 + r) * D + n0 + m] = s2 / rowsum[quad * 4 + r];
      }
    }
  }
}

// ---------------------------------------------------------------------------
extern "C" void kernel_launch(void* const* d_in, const int* in_sizes, int n_in,
                              void* d_out, int out_size, void* d_ws, size_t ws_size,
                              hipStream_t stream) {
  const float* q = (const float*)d_in[0];
  const float* k = (const float*)d_in[1];
  const float* v = (const float*)d_in[2];
  float* out = (float*)d_out;
  float* attn = out + (size_t)BH * N * D;  // attn_p region of d_out

  const size_t PLANE = (size_t)BH * N * D;  // 2,097,152 elems
  const size_t need = PLANE * 6 * sizeof(u16);  // 24 MB
  if (ws_size >= need && d_ws != nullptr) {
    u16* base = (u16*)d_ws;
    u16* qhP = base;
    u16* qlP = base + PLANE;
    u16* khP = base + 2 * PLANE;
    u16* klP = base + 3 * PLANE;
    u16* vThP = base + 4 * PLANE;
    u16* vTlP = base + 5 * PLANE;
    prep_qk<<<dim3((unsigned)(PLANE / 1024)), 256, 0, stream>>>(q, k, qhP, qlP, khP, klP);
    prep_v<<<dim3(N / 64, BH), 256, 0, stream>>>(v, vThP, vTlP);
    fused_attn_pl<<<dim3(N / ROWS, BH), 1024, 0, stream>>>(qhP, qlP, khP, klP, vThP, vTlP, out, attn);
  } else {
    fused_attn_fb<<<dim3(N / ROWS, BH), 512, 0, stream>>>(q, k, v, out, attn);
  }
}

// Round 4
// 609.931 us; speedup vs baseline: 1.3749x; 1.0461x over previous
//
#include <hip/hip_runtime.h>

#define N 2048
#define D 64
#define BH 16
#define NWORDS 3126          // bitmap words over r in [0,100000]
#define ROWS 16              // score rows per block
#define SCP 2052             // score-row pitch in floats (+4 pad -> bank rotation)
#define AUXW (2 * NWORDS)    // 6252 words multi-purpose LDS (bitmaps / scratch)

typedef __bf16 bf16x8 __attribute__((ext_vector_type(8)));
typedef float f32x4 __attribute__((ext_vector_type(4)));
typedef unsigned short u16;

union Bf16x8U {
  bf16x8 v;
  __bf16 e[8];
  u16 us[8];
};

union U32x4Bf {
  unsigned u[4];
  bf16x8 v;
};

// Split 8 fp32 (two float4) into hi/lo bf16 fragments: f = hi + lo + O(2^-16 f)
static __device__ inline void split8(const float4& a, const float4& b,
                                     bf16x8& hi, bf16x8& lo) {
  float f[8] = {a.x, a.y, a.z, a.w, b.x, b.y, b.z, b.w};
  Bf16x8U h, l;
#pragma unroll
  for (int i = 0; i < 8; ++i) {
    __bf16 hb = (__bf16)f[i];
    h.e[i] = hb;
    l.e[i] = (__bf16)(f[i] - (float)hb);
  }
  hi = h.v;
  lo = l.v;
}

// ---------------------------------------------------------------------------
// Prep 1: q -> scaled hi/lo bf16 planes; k -> hi/lo bf16 planes (same layout).
// ---------------------------------------------------------------------------
__global__ __launch_bounds__(256) void prep_qk(
    const float* __restrict__ q, const float* __restrict__ k,
    u16* __restrict__ qhP, u16* __restrict__ qlP,
    u16* __restrict__ khP, u16* __restrict__ klP) {
  const size_t i = ((size_t)blockIdx.x * 256 + threadIdx.x) * 4;
  float4 qv = *(const float4*)(q + i);
  float4 kv = *(const float4*)(k + i);
  float fq[4] = {qv.x * 0.125f, qv.y * 0.125f, qv.z * 0.125f, qv.w * 0.125f};
  float fk[4] = {kv.x, kv.y, kv.z, kv.w};
  union { ushort4 v; u16 e[4]; } qh4, ql4, kh4, kl4;
#pragma unroll
  for (int j = 0; j < 4; ++j) {
    __bf16 qhb = (__bf16)fq[j];
    qh4.e[j] = __builtin_bit_cast(u16, qhb);
    ql4.e[j] = __builtin_bit_cast(u16, (__bf16)(fq[j] - (float)qhb));
    __bf16 khb = (__bf16)fk[j];
    kh4.e[j] = __builtin_bit_cast(u16, khb);
    kl4.e[j] = __builtin_bit_cast(u16, (__bf16)(fk[j] - (float)khb));
  }
  *(ushort4*)(qhP + i) = qh4.v;
  *(ushort4*)(qlP + i) = ql4.v;
  *(ushort4*)(khP + i) = kh4.v;
  *(ushort4*)(klP + i) = kl4.v;
}

// ---------------------------------------------------------------------------
// Prep 2: v[h][k][n] -> vT{h,l}[h][n][k] bf16 planes (transpose + split).
// ---------------------------------------------------------------------------
__global__ __launch_bounds__(256) void prep_v(
    const float* __restrict__ v, u16* __restrict__ vThP, u16* __restrict__ vTlP) {
  const int h = blockIdx.y;
  const int k0 = blockIdx.x * 64;
  const int t = threadIdx.x;
  const int n = t >> 2;
  const int g = t & 3;
  const float* vp = v + (size_t)h * N * D + (size_t)(k0 + g * 16) * D + n;
  union { uint4 u4[2]; u16 us[16]; } H, L;
#pragma unroll
  for (int j = 0; j < 16; ++j) {
    float f = vp[(size_t)j * D];
    __bf16 hb = (__bf16)f;
    H.us[j] = __builtin_bit_cast(u16, hb);
    L.us[j] = __builtin_bit_cast(u16, (__bf16)(f - (float)hb));
  }
  const size_t o = (size_t)h * D * N + (size_t)n * N + k0 + g * 16;
  *(uint4*)(vThP + o) = H.u4[0];
  *(uint4*)(vThP + o + 8) = H.u4[1];
  *(uint4*)(vTlP + o) = L.u4[0];
  *(uint4*)(vTlP + o + 8) = L.u4[1];
}

// ---------------------------------------------------------------------------
// Fused attention, plane-fed, 1024 threads (16 waves -> 4 waves/SIMD).
// VALU-diet version: __expf, divides -> multiplies, P rows stored packed
// (bf16hi<<16 | bf16lo) in sc so PV unpacks with bit-ops instead of split8;
// attn_p written once at kernel end (no per-iter store-drain at barriers).
// ---------------------------------------------------------------------------
__global__ __launch_bounds__(1024) void fused_attn_pl(
    const u16* __restrict__ qhP, const u16* __restrict__ qlP,
    const u16* __restrict__ khP, const u16* __restrict__ klP,
    const u16* __restrict__ vThP, const u16* __restrict__ vTlP,
    float* __restrict__ outp, float* __restrict__ attnp) {
  __shared__ float sc[ROWS * SCP];   // 131,328 B score tile (f32, then packed u32)
  __shared__ unsigned aux[AUXW];     // 25,008 B: P3 bitmaps / P4 scratch
  __shared__ float rowmax[ROWS];
  __shared__ float rowsum[ROWS];

  const int h = blockIdx.y;
  const int row0 = blockIdx.x * ROWS;
  const int t = threadIdx.x;
  const int wave = t >> 6;       // 0..15
  const int lane = t & 63;
  const int m = lane & 15;
  const int quad = lane >> 4;

  // ================= Phase 1: sc = (q/8) @ k^T from planes =================
  {
    const size_t hb = (size_t)h * N * D;
    const size_t qoff = hb + (size_t)(row0 + m) * D + quad * 8;
    bf16x8 ahi0 = *(const bf16x8*)(qhP + qoff);
    bf16x8 ahi1 = *(const bf16x8*)(qhP + qoff + 32);
    bf16x8 alo0 = *(const bf16x8*)(qlP + qoff);
    bf16x8 alo1 = *(const bf16x8*)(qlP + qoff + 32);

    const int colbase = wave * 128;  // wave covers 8 col-tiles
    const u16* khh = khP + hb;
    const u16* kll = klP + hb;
    size_t off = (size_t)(colbase + m) * D + quad * 8;
    bf16x8 bhi0 = *(const bf16x8*)(khh + off);
    bf16x8 bhi1 = *(const bf16x8*)(khh + off + 32);
    bf16x8 blo0 = *(const bf16x8*)(kll + off);
    bf16x8 blo1 = *(const bf16x8*)(kll + off + 32);
#pragma unroll
    for (int ct = 0; ct < 8; ++ct) {
      bf16x8 nhi0, nhi1, nlo0, nlo1;
      if (ct < 7) {  // 1-deep prefetch of next k col-tile
        const size_t noff = off + (size_t)16 * D;
        nhi0 = *(const bf16x8*)(khh + noff);
        nhi1 = *(const bf16x8*)(khh + noff + 32);
        nlo0 = *(const bf16x8*)(kll + noff);
        nlo1 = *(const bf16x8*)(kll + noff + 32);
      }
      f32x4 c = {0.f, 0.f, 0.f, 0.f};
      // same accumulation order as the verified kernels
      c = __builtin_amdgcn_mfma_f32_16x16x32_bf16(alo0, bhi0, c, 0, 0, 0);
      c = __builtin_amdgcn_mfma_f32_16x16x32_bf16(alo1, bhi1, c, 0, 0, 0);
      c = __builtin_amdgcn_mfma_f32_16x16x32_bf16(ahi0, blo0, c, 0, 0, 0);
      c = __builtin_amdgcn_mfma_f32_16x16x32_bf16(ahi1, blo1, c, 0, 0, 0);
      c = __builtin_amdgcn_mfma_f32_16x16x32_bf16(ahi0, bhi0, c, 0, 0, 0);
      c = __builtin_amdgcn_mfma_f32_16x16x32_bf16(ahi1, bhi1, c, 0, 0, 0);
      const int cb = colbase + ct * 16 + m;
#pragma unroll
      for (int r = 0; r < 4; ++r) sc[(quad * 4 + r) * SCP + cb] = c[r];
      bhi0 = nhi0; bhi1 = nhi1; blo0 = nlo0; blo1 = nlo1;
      off += (size_t)16 * D;
    }
  }
  __syncthreads();

  // ================= Phase 2: per-row max (wave w -> row w) ================
  {
    const int r = wave;
    const float* rowp = &sc[r * SCP];
    float mx = -3.4e38f;
#pragma unroll
    for (int i = 0; i < 8; ++i) {
      float4 vv = *(const float4*)&rowp[(lane + i * 64) * 4];
      mx = fmaxf(mx, fmaxf(fmaxf(vv.x, vv.y), fmaxf(vv.z, vv.w)));
    }
#pragma unroll
    for (int o = 32; o > 0; o >>= 1) mx = fmaxf(mx, __shfl_xor(mx, o, 64));
    if (lane == 0) rowmax[r] = mx;
  }
  __syncthreads();

  // ====== Phase 3: exp -> round -> bitmap dedup-sum; pack row into sc ======
  // 2 rows concurrently, 512 threads (8 waves) per row, 4 elems/thread.
  {
    const int g = wave >> 3;   // waves 0-7 -> rows 0..7, waves 8-15 -> rows 8..15
    const int tt = t & 511;
    unsigned* bm = aux + g * NWORDS;
#pragma unroll 1
    for (int it = 0; it < 8; ++it) {
      const int r = it + g * 8;
      for (int i = tt; i < NWORDS; i += 512) bm[i] = 0u;
      if (tt == 0) rowsum[r] = 0.0f;
      __syncthreads();
      const float mrow = rowmax[r];
      float* rowp = &sc[r * SCP];
      float4 x0 = *(const float4*)&rowp[tt * 4];
      float xs[4] = {x0.x, x0.y, x0.z, x0.w};
      unsigned pk[4];
      float lsum = 0.0f;
#pragma unroll
      for (int j = 0; j < 4; ++j) {
        float ex = __expf(xs[j] - mrow);         // <= 1.0; ~2ulp vs libm, far
                                                 // below the 1e-5 round grid
        float rf = rintf(ex * 100000.0f);        // round-half-even, exact in fp32
        float xv = rf * 1e-5f;                   // <=1ulp vs divide; injective in rf
        int ri = (int)rf;                        // 0..100000
        unsigned mask = 1u << (ri & 31);
        unsigned old = atomicOr(&bm[ri >> 5], mask);
        if (!(old & mask)) lsum += xv;           // each distinct value once
        // pack bf16 hi/lo split (identical values split8 would produce)
        __bf16 hb = (__bf16)xv;
        __bf16 lb = (__bf16)(xv - (float)hb);
        pk[j] = ((unsigned)__builtin_bit_cast(u16, hb) << 16) |
                (unsigned)__builtin_bit_cast(u16, lb);
      }
      // write packed row back (PV + final attn_p store consume this)
      *(uint4*)&rowp[tt * 4] = make_uint4(pk[0], pk[1], pk[2], pk[3]);
#pragma unroll
      for (int o = 32; o > 0; o >>= 1) lsum += __shfl_xor(lsum, o, 64);
      if (lane == 0) atomicAdd(&rowsum[r], lsum);
      __syncthreads();
    }
  }
  // (last __syncthreads of the loop orders all packed writes before PV)

  // ===== Phase 4: PV on unnormalized xv, B streamed from vT planes =========
  // wave = ksub*4 + ctn: ctn = col-tile (16 cols), ksub = K-quarter (512).
  {
    const int ctn = wave & 3;
    const int ksub = wave >> 2;        // 0..3
    const int n0 = ctn * 16;
    const u16* vhh = vThP + (size_t)h * D * N + (size_t)(n0 + m) * N;
    const u16* vll = vTlP + (size_t)h * D * N + (size_t)(n0 + m) * N;
    f32x4 acc = {0.f, 0.f, 0.f, 0.f};

    const int kbeg = ksub * 512;
    int kk = kbeg + quad * 8;
    bf16x8 bh = *(const bf16x8*)(vhh + kk);
    bf16x8 bl = *(const bf16x8*)(vll + kk);
#pragma unroll 2
    for (int k0 = kbeg; k0 < kbeg + 512; k0 += 32) {
      bf16x8 nbh, nbl;
      if (k0 + 32 < kbeg + 512) {  // 1-deep prefetch (L2-resident)
        nbh = *(const bf16x8*)(vhh + kk + 32);
        nbl = *(const bf16x8*)(vll + kk + 32);
      }
      // A fragment: unpack packed hi/lo words with pure bit-ops
      const unsigned* ap = (const unsigned*)&sc[(size_t)m * SCP + k0 + quad * 8];
      uint4 w0 = *(const uint4*)(ap);
      uint4 w1 = *(const uint4*)(ap + 4);
      U32x4Bf AH, AL;
      AH.u[0] = (w0.x >> 16) | (w0.y & 0xffff0000u);
      AH.u[1] = (w0.z >> 16) | (w0.w & 0xffff0000u);
      AH.u[2] = (w1.x >> 16) | (w1.y & 0xffff0000u);
      AH.u[3] = (w1.z >> 16) | (w1.w & 0xffff0000u);
      AL.u[0] = (w0.x & 0xffffu) | (w0.y << 16);
      AL.u[1] = (w0.z & 0xffffu) | (w0.w << 16);
      AL.u[2] = (w1.x & 0xffffu) | (w1.y << 16);
      AL.u[3] = (w1.z & 0xffffu) | (w1.w << 16);
      acc = __builtin_amdgcn_mfma_f32_16x16x32_bf16(AL.v, bh, acc, 0, 0, 0);
      acc = __builtin_amdgcn_mfma_f32_16x16x32_bf16(AH.v, bl, acc, 0, 0, 0);
      acc = __builtin_amdgcn_mfma_f32_16x16x32_bf16(AH.v, bh, acc, 0, 0, 0);
      bh = nbh; bl = nbl;
      kk += 32;
    }

    // ---- reduce 4 K-quarter partials per col-tile -------------------------
    float* fscr = (float*)aux;   // 12 x 256 floats
    if (ksub > 0) {
#pragma unroll
      for (int r = 0; r < 4; ++r)
        fscr[((ksub - 1) * 4 + ctn) * 256 + lane * 4 + r] = acc[r];
    }
    __syncthreads();
    if (ksub == 0) {
      float* oh = outp + (size_t)h * N * D;
#pragma unroll
      for (int r = 0; r < 4; ++r) {
        float s2 = acc[r]
                 + fscr[(0 * 4 + ctn) * 256 + lane * 4 + r]
                 + fscr[(1 * 4 + ctn) * 256 + lane * 4 + r]
                 + fscr[(2 * 4 + ctn) * 256 + lane * 4 + r];
        oh[(size_t)(row0 + quad * 4 + r) * D + n0 + m] = s2 / rowsum[quad * 4 + r];
      }
    }
  }

  // ===== Phase 5: attn_p = (hi+lo) * (1/total) -> global, fire-and-forget ==
  // Reconstruction error <= xv * 2^-18 -- far below tolerance. No barriers
  // after this; store acks drain at kernel end.
  {
    const int g = wave >> 3;
    const int tt = t & 511;
#pragma unroll 1
    for (int it = 0; it < 8; ++it) {
      const int r = it + g * 8;
      const float inv = 1.0f / rowsum[r];
      const unsigned* rowp = (const unsigned*)&sc[r * SCP];
      uint4 w = *(const uint4*)&rowp[tt * 4];
      float4 o;
      o.x = (__builtin_bit_cast(float, w.x & 0xffff0000u) +
             __builtin_bit_cast(float, w.x << 16)) * inv;
      o.y = (__builtin_bit_cast(float, w.y & 0xffff0000u) +
             __builtin_bit_cast(float, w.y << 16)) * inv;
      o.z = (__builtin_bit_cast(float, w.z & 0xffff0000u) +
             __builtin_bit_cast(float, w.z << 16)) * inv;
      o.w = (__builtin_bit_cast(float, w.w & 0xffff0000u) +
             __builtin_bit_cast(float, w.w << 16)) * inv;
      float4* dst = (float4*)(attnp + ((size_t)h * N + row0 + r) * N);
      dst[tt] = o;
    }
  }
}

// ---------------------------------------------------------------------------
// Fallback (verified round-1 kernel, used only if ws_size < 24 MB).
// ---------------------------------------------------------------------------
__global__ __launch_bounds__(512) void fused_attn_fb(
    const float* __restrict__ q, const float* __restrict__ k,
    const float* __restrict__ v, float* __restrict__ outp,
    float* __restrict__ attnp) {
  __shared__ float sc[ROWS * SCP];
  __shared__ unsigned aux[AUXW];
  __shared__ float rowmax[ROWS];
  __shared__ float rowsum[ROWS];

  const int h = blockIdx.y;
  const int row0 = blockIdx.x * ROWS;
  const float* qh = q + (size_t)h * N * D;
  const float* kh = k + (size_t)h * N * D;
  const float* vh = v + (size_t)h * N * D;

  const int t = threadIdx.x;
  const int wave = t >> 6;
  const int lane = t & 63;
  const int m = lane & 15;
  const int quad = lane >> 4;

  {
    float* qlds = (float*)aux;
    if (t < 256) {
      const int qr = t >> 4;
      const int qc = (t & 15) * 4;
      float4 vv = *(const float4*)(qh + (size_t)(row0 + qr) * D + qc);
      vv.x *= 0.125f; vv.y *= 0.125f; vv.z *= 0.125f; vv.w *= 0.125f;
      *(float4*)&qlds[qr * 68 + qc] = vv;
    }
    __syncthreads();

    bf16x8 ahi0, alo0, ahi1, alo1;
    {
      const float* qp = &qlds[m * 68 + quad * 8];
      float4 a00 = *(const float4*)(qp);
      float4 a01 = *(const float4*)(qp + 4);
      float4 a10 = *(const float4*)(qp + 32);
      float4 a11 = *(const float4*)(qp + 36);
      split8(a00, a01, ahi0, alo0);
      split8(a10, a11, ahi1, alo1);
    }

    const int colbase = wave * 256;
    float4 c0, c1, c2, c3, p0, p1, p2, p3;
    {
      const float* kr = kh + (size_t)(colbase + m) * D + quad * 8;
      c0 = *(const float4*)(kr);
      c1 = *(const float4*)(kr + 4);
      c2 = *(const float4*)(kr + 32);
      c3 = *(const float4*)(kr + 36);
    }
#pragma unroll
    for (int ct = 0; ct < 16; ++ct) {
      if (ct < 15) {
        const float* kr = kh + (size_t)(colbase + (ct + 1) * 16 + m) * D + quad * 8;
        p0 = *(const float4*)(kr);
        p1 = *(const float4*)(kr + 4);
        p2 = *(const float4*)(kr + 32);
        p3 = *(const float4*)(kr + 36);
      }
      bf16x8 bhi0, blo0, bhi1, blo1;
      split8(c0, c1, bhi0, blo0);
      split8(c2, c3, bhi1, blo1);
      f32x4 acc = {0.f, 0.f, 0.f, 0.f};
      acc = __builtin_amdgcn_mfma_f32_16x16x32_bf16(alo0, bhi0, acc, 0, 0, 0);
      acc = __builtin_amdgcn_mfma_f32_16x16x32_bf16(alo1, bhi1, acc, 0, 0, 0);
      acc = __builtin_amdgcn_mfma_f32_16x16x32_bf16(ahi0, blo0, acc, 0, 0, 0);
      acc = __builtin_amdgcn_mfma_f32_16x16x32_bf16(ahi1, blo1, acc, 0, 0, 0);
      acc = __builtin_amdgcn_mfma_f32_16x16x32_bf16(ahi0, bhi0, acc, 0, 0, 0);
      acc = __builtin_amdgcn_mfma_f32_16x16x32_bf16(ahi1, bhi1, acc, 0, 0, 0);
      const int cb = colbase + ct * 16 + m;
#pragma unroll
      for (int r = 0; r < 4; ++r) sc[(quad * 4 + r) * SCP + cb] = acc[r];
      c0 = p0; c1 = p1; c2 = p2; c3 = p3;
    }
  }
  __syncthreads();

#pragma unroll
  for (int rr = 0; rr < 2; ++rr) {
    const int r = wave + rr * 8;
    const float* rowp = &sc[r * SCP];
    float mx = -3.4e38f;
#pragma unroll
    for (int i = 0; i < 8; ++i) {
      float4 vv = *(const float4*)&rowp[(lane + i * 64) * 4];
      mx = fmaxf(mx, fmaxf(fmaxf(vv.x, vv.y), fmaxf(vv.z, vv.w)));
    }
#pragma unroll
    for (int o = 32; o > 0; o >>= 1) mx = fmaxf(mx, __shfl_xor(mx, o, 64));
    if (lane == 0) rowmax[r] = mx;
  }
  __syncthreads();

  {
    const int g = wave >> 2;
    const int tt = t & 255;
    unsigned* bm = aux + g * NWORDS;
#pragma unroll 1
    for (int it = 0; it < 8; ++it) {
      const int r = it + g * 8;
      for (int i = tt; i < NWORDS; i += 256) bm[i] = 0u;
      if (tt == 0) rowsum[r] = 0.0f;
      __syncthreads();
      const float mrow = rowmax[r];
      float* rowp = &sc[r * SCP];
      float4 x0 = *(const float4*)&rowp[tt * 4];
      float4 x1 = *(const float4*)&rowp[1024 + tt * 4];
      float xs[8] = {x0.x, x0.y, x0.z, x0.w, x1.x, x1.y, x1.z, x1.w};
      float xr[8];
      float lsum = 0.0f;
#pragma unroll
      for (int j = 0; j < 8; ++j) {
        float ex = expf(xs[j] - mrow);
        float rf = rintf(ex * 100000.0f);
        float xv = rf / 100000.0f;
        xr[j] = xv;
        int ri = (int)rf;
        unsigned mask = 1u << (ri & 31);
        unsigned old = atomicOr(&bm[ri >> 5], mask);
        if (!(old & mask)) lsum += xv;
      }
      *(float4*)&rowp[tt * 4] = make_float4(xr[0], xr[1], xr[2], xr[3]);
      *(float4*)&rowp[1024 + tt * 4] = make_float4(xr[4], xr[5], xr[6], xr[7]);
#pragma unroll
      for (int o = 32; o > 0; o >>= 1) lsum += __shfl_xor(lsum, o, 64);
      if (lane == 0) atomicAdd(&rowsum[r], lsum);
      __syncthreads();
      const float total = rowsum[r];
      float4* dst = (float4*)(attnp + ((size_t)h * N + row0 + r) * N);
      dst[tt] = make_float4(xr[0] / total, xr[1] / total, xr[2] / total, xr[3] / total);
      dst[256 + tt] = make_float4(xr[4] / total, xr[5] / total, xr[6] / total, xr[7] / total);
    }
  }
  __syncthreads();

  {
    unsigned* vpack = aux;  // [64][65] packed (hi<<16)|lo
    const int skk = t >> 4;
    const int snn = (t & 15) * 4;
    const int ctn = wave & 3;
    const int ksub = wave >> 2;
    const int n0 = ctn * 16;
    f32x4 acc = {0.f, 0.f, 0.f, 0.f};

#pragma unroll 1
    for (int k0 = 0; k0 < N; k0 += 64) {
      __syncthreads();
#pragma unroll
      for (int i = 0; i < 2; ++i) {
        int kk = skk + i * 32;
        float4 vv = *(const float4*)(vh + (size_t)(k0 + kk) * D + snn);
        float f[4] = {vv.x, vv.y, vv.z, vv.w};
#pragma unroll
        for (int j = 0; j < 4; ++j) {
          __bf16 hb = (__bf16)f[j];
          __bf16 lb = (__bf16)(f[j] - (float)hb);
          unsigned hu = (unsigned)__builtin_bit_cast(u16, hb);
          unsigned lu = (unsigned)__builtin_bit_cast(u16, lb);
          vpack[(size_t)kk * 65 + snn + j] = (hu << 16) | lu;
        }
      }
      __syncthreads();

      const float* ap = &sc[(size_t)m * SCP + k0 + ksub * 32 + quad * 8];
      float4 a0 = *(const float4*)(ap);
      float4 a1 = *(const float4*)(ap + 4);
      bf16x8 ahi, alo;
      split8(a0, a1, ahi, alo);

      Bf16x8U bhh, bll;
#pragma unroll
      for (int j = 0; j < 8; ++j) {
        unsigned u = vpack[(size_t)(ksub * 32 + quad * 8 + j) * 65 + n0 + m];
        bhh.us[j] = (u16)(u >> 16);
        bll.us[j] = (u16)(u & 0xffffu);
      }
      acc = __builtin_amdgcn_mfma_f32_16x16x32_bf16(alo, bhh.v, acc, 0, 0, 0);
      acc = __builtin_amdgcn_mfma_f32_16x16x32_bf16(ahi, bll.v, acc, 0, 0, 0);
      acc = __builtin_amdgcn_mfma_f32_16x16x32_bf16(ahi, bhh.v, acc, 0, 0, 0);
    }
    __syncthreads();

    float* fscr = (float*)aux;
    if (wave >= 4) {
#pragma unroll
      for (int r = 0; r < 4; ++r) fscr[(wave - 4) * 256 + lane * 4 + r] = acc[r];
    }
    __syncthreads();
    if (wave < 4) {
      float* oh = outp + (size_t)h * N * D;
#pragma unroll
      for (int r = 0; r < 4; ++r) {
        float s2 = acc[r] + fscr[wave * 256 + lane * 4 + r];
        oh[(size_t)(row0 + quad * 4 + r) * D + n0 + m] = s2 / rowsum[quad * 4 + r];
      }
    }
  }
}

// ---------------------------------------------------------------------------
extern "C" void kernel_launch(void* const* d_in, const int* in_sizes, int n_in,
                              void* d_out, int out_size, void* d_ws, size_t ws_size,
                              hipStream_t stream) {
  const float* q = (const float*)d_in[0];
  const float* k = (const float*)d_in[1];
  const float* v = (const float*)d_in[2];
  float* out = (float*)d_out;
  float* attn = out + (size_t)BH * N * D;  // attn_p region of d_out

  const size_t PLANE = (size_t)BH * N * D;  // 2,097,152 elems
  const size_t need = PLANE * 6 * sizeof(u16);  // 24 MB
  if (ws_size >= need && d_ws != nullptr) {
    u16* base = (u16*)d_ws;
    u16* qhP = base;
    u16* qlP = base + PLANE;
    u16* khP = base + 2 * PLANE;
    u16* klP = base + 3 * PLANE;
    u16* vThP = base + 4 * PLANE;
    u16* vTlP = base + 5 * PLANE;
    prep_qk<<<dim3((unsigned)(PLANE / 1024)), 256, 0, stream>>>(q, k, qhP, qlP, khP, klP);
    prep_v<<<dim3(N / 64, BH), 256, 0, stream>>>(v, vThP, vTlP);
    fused_attn_pl<<<dim3(N / ROWS, BH), 1024, 0, stream>>>(qhP, qlP, khP, klP, vThP, vTlP, out, attn);
  } else {
    fused_attn_fb<<<dim3(N / ROWS, BH), 512, 0, stream>>>(q, k, v, out, attn);
  }
}